// Round 8
// baseline (2125.133 us; speedup 1.0000x reference)
//
#include <hip/hip_runtime.h>
#include <math.h>

// Problem constants
#define VV 32000   // vocab
#define SS 512     // states
#define BB 64      // batch
#define TT 256     // maxlen
#define WSLOT (BB * SS)  // floats per w time-slot (32768)
#define B_BURN 24  // burn-in steps per segment (contraction ~0.46^24 ~ 2e-8)

// ---------------- setup kernels ----------------

// Column sums of exp(iw) over vocab rows. Block 0 also hosts one-time zero
// duties (out, colsum, flags) — consumers run in later kernels (stream order).
__global__ void k_colpart(const float* __restrict__ iw, float* __restrict__ psum,
                          float* __restrict__ out, float* __restrict__ colsum,
                          unsigned* __restrict__ flags) {
  const int blk = blockIdx.x;        // 250
  const int tid = threadIdx.x;       // 256
  if (blk == 0) {
    if (tid == 0) out[0] = 0.f;
    flags[tid] = 0u; flags[tid + 256] = 0u;       // 512 flags (L/H x 8 segs x 32)
    colsum[tid] = 0.f; colsum[tid + 256] = 0.f;
  }
  const int cg = tid & 127;          // float4 column group
  const int rh = tid >> 7;           // row half
  const int r0 = blk * 128 + rh * 64;
  const float4* iw4 = (const float4*)iw;   // [32000][128] float4
  float4 s = make_float4(0.f, 0.f, 0.f, 0.f);
  #pragma unroll 4
  for (int r = 0; r < 64; ++r) {
    float4 x = iw4[(size_t)(r0 + r) * 128 + cg];
    s.x += __expf(x.x); s.y += __expf(x.y); s.z += __expf(x.z); s.w += __expf(x.w);
  }
  ((float4*)psum)[(size_t)(blk * 2 + rh) * 128 + cg] = s;
}

// 25 blocks x 512 thr: block p sums partial rows [20p, 20p+20) -> atomicAdd.
__global__ void k_colreduce(const float* __restrict__ psum, float* __restrict__ colsum) {
  const int c = threadIdx.x;         // 512
  const int p0 = blockIdx.x * 20;
  float s = 0.f;
  #pragma unroll 5
  for (int p = 0; p < 20; ++p) s += psum[(size_t)(p0 + p) * SS + c];
  atomicAdd(&colsum[c], s);
}

// P[i][j] = softmax(transition[i,:])[j] (row-major), q0vec[i] = sum_j P[i,j]*sb[j].
__global__ void k_transP(const float* __restrict__ trans, const float* __restrict__ begin,
                         float* __restrict__ P, float* __restrict__ q0vec) {
  const int i = blockIdx.x;     // 512 rows
  const int lane = threadIdx.x; // 64
  // local softmax(begin)
  float bx[8];
  float bm = -1e30f;
  #pragma unroll
  for (int cc = 0; cc < 8; ++cc) { bx[cc] = begin[cc * 64 + lane]; bm = fmaxf(bm, bx[cc]); }
  #pragma unroll
  for (int o = 32; o; o >>= 1) bm = fmaxf(bm, __shfl_xor(bm, o));
  float bs = 0.f;
  #pragma unroll
  for (int cc = 0; cc < 8; ++cc) { bx[cc] = __expf(bx[cc] - bm); bs += bx[cc]; }
  #pragma unroll
  for (int o = 32; o; o >>= 1) bs += __shfl_xor(bs, o);
  const float binv = 1.f / bs;

  const float* rp = trans + (size_t)i * SS;
  float xs[8];
  float m = -1e30f;
  #pragma unroll
  for (int cc = 0; cc < 8; ++cc) { xs[cc] = rp[cc * 64 + lane]; m = fmaxf(m, xs[cc]); }
  #pragma unroll
  for (int o = 32; o; o >>= 1) m = fmaxf(m, __shfl_xor(m, o));
  float s = 0.f;
  #pragma unroll
  for (int cc = 0; cc < 8; ++cc) s += __expf(xs[cc] - m);
  #pragma unroll
  for (int o = 32; o; o >>= 1) s += __shfl_xor(s, o);
  const float lse = m + __logf(s);
  float qa = 0.f;
  #pragma unroll
  for (int cc = 0; cc < 8; ++cc) {
    float p = __expf(xs[cc] - lse);
    P[(size_t)i * SS + cc * 64 + lane] = p;
    qa += p * (bx[cc] * binv);
  }
  #pragma unroll
  for (int o = 32; o; o >>= 1) qa += __shfl_xor(qa, o);
  if (lane == 0) q0vec[i] = qa;
}

// ---------------- persistent segmented-chain kernel ----------------
// 256 blocks = 8 segments x 32 blocks. seg = blk&7 (likely XCD-local; locality
// heuristic only). Segment -> (chain c = seg&1, quarter q = seg>>1).
// Chain-even k-ranges: [0,33) [33,65) [65,97) [97,129); chain-odd: 32-strided.
// Segments q>0 prepend B_BURN burn-in steps from uniform init w=1/64 (valid:
// batch-col-sums = 1). Burn-in writes a PRIVATE scratch ring and skips
// dotpart; the Birkhoff contraction of P (tanh(diam/4) ~ 0.46/step) shrinks
// the init error below fp32 rounding by the first exact step.
// Each block owns 16 states. Sync fabric = R3/R7's proven shape: single
// sleepy scout (wave 0) polls its segment's 64 flag words (32 L + 32 H) with
// ONE load + __all between two barriers; own-flag skip. Producers: wave 0 ->
// w states [0,8), flagL; wave 1 -> [8,16), flagH; wave 2 -> dotpart.
// w ring WRITE-ONCE per launch (slot = timestep); launch-boundary acquire
// invalidates L2s, and in-launch streaming (>>4MB/XCD) self-evicts.
__global__ __launch_bounds__(256) void k_persist(
    const float* __restrict__ P, const float* __restrict__ q0vec,
    const float* __restrict__ iw, const float* __restrict__ colsum,
    const int* __restrict__ sent, float* __restrict__ wring,
    float* __restrict__ dotpart, unsigned* __restrict__ flags) {
  const int blk = blockIdx.x;
  const int seg = blk & 7;             // likely == XCD id (heuristic)
  const int sblk = blk >> 3;           // 0..31
  const int c = seg & 1;
  const int q = seg >> 1;              // 0..3
  const int lane = threadIdx.x & 63;   // batch b
  const int h = __builtin_amdgcn_readfirstlane(threadIdx.x >> 6);
  const int i0 = sblk << 4;            // 16 states per block

  const int kend = (c == 0) ? (33 + 32 * q) : (32 * (q + 1));
  const int kbeg = (c == 0) ? (q ? (1 + 32 * q) : 0) : (32 * q);
  const int kfirst = q ? (kbeg - B_BURN) : 0;

  unsigned* const flagL = flags + seg * 32;
  unsigned* const flagH = flags + 256 + seg * 32;
  unsigned* const pollp = flags + seg * 32 + ((lane < 32) ? lane : (224 + lane));
  const bool own = ((lane & 31) == sblk);

  float cl[16];
  #pragma unroll
  for (int r = 0; r < 16; ++r) cl[r] = __logf(colsum[i0 + r]);

  const float4* Pq[16];
  #pragma unroll
  for (int r = 0; r < 16; ++r)
    Pq[r] = (const float4*)(P + (size_t)(i0 + r) * SS) + h * 32;

  float* const wmain = wring;
  float* const wscr  = wring + (size_t)TT * WSLOT;

  __shared__ float4 red[4][4][64];   // [state-quad][wave][lane]

  for (int kk = kfirst; kk < kend; ++kk) {
    const int tw = 2 * kk + c;
    const bool exact = (kk >= kbeg);
    const bool doW = (h <= 1) && (kk + 1 < kend);
    const bool doD = (h == 2) && exact && (tw >= 1);
    const int off = (h == 1) ? 8 : 0;

    // iw gathers issued before the sync phase — L2/L3 latency hides there.
    float4 iv0 = make_float4(0.f,0.f,0.f,0.f), iv1 = iv0, iv2 = iv0, iv3 = iv0;
    if (doW) {
      const int row = sent[lane * TT + tw];
      const float* ip = iw + (size_t)row * SS + i0 + off;
      iv0 = *(const float4*)ip;
      iv1 = *(const float4*)(ip + 4);
    } else if (doD) {
      const int row = sent[lane * TT + (tw - 1)];
      const float* ip = iw + (size_t)row * SS + i0;
      iv0 = *(const float4*)ip;
      iv1 = *(const float4*)(ip + 4);
      iv2 = *(const float4*)(ip + 8);
      iv3 = *(const float4*)(ip + 12);
    }

    if (kk > kfirst) {
      __syncthreads();  // previous epilogue + red reads complete
      if (h == 0) {
        const unsigned tgt = (unsigned)kk;  // predecessor stored kk
        for (;;) {
          const unsigned v = __hip_atomic_load(pollp, __ATOMIC_RELAXED,
                                               __HIP_MEMORY_SCOPE_AGENT);
          if (__all(own || (v >= tgt))) break;
          __builtin_amdgcn_s_sleep(2);
        }
      }
      __syncthreads();
    }

    float a[16];
    if (kk == 0) {                       // exact init (seg q=0)
      #pragma unroll
      for (int r = 0; r < 16; ++r) a[r] = (h == 0) ? q0vec[i0 + r] : 0.f;
    } else if (kk == kfirst) {           // burn-in init: w_prev = 1/64 uniform
      #pragma unroll                     // => P*w = 1/64 (rows sum to 1)
      for (int r = 0; r < 16; ++r) a[r] = (h == 0) ? 0.015625f : 0.f;
    } else {
      const float* wsrc = ((kk - 1) >= kbeg) ? wmain : wscr;
      const float4* wv = (const float4*)(wsrc + (size_t)(tw - 2) * WSLOT)
                         + h * 32 * 64;
      float4 wr[32];
      #pragma unroll
      for (int u = 0; u < 32; ++u) wr[u] = wv[u * 64 + lane];
      #pragma unroll
      for (int r = 0; r < 16; ++r) a[r] = 0.f;
      #pragma unroll
      for (int u = 0; u < 32; ++u) {
        #pragma unroll
        for (int r = 0; r < 16; ++r) {
          const float4 p = Pq[r][u];
          a[r] += wr[u].x * p.x + wr[u].y * p.y + wr[u].z * p.z + wr[u].w * p.w;
        }
      }
    }

    #pragma unroll
    for (int rq = 0; rq < 4; ++rq)
      red[rq][h][lane] = make_float4(a[4*rq], a[4*rq+1], a[4*rq+2], a[4*rq+3]);
    __syncthreads();

    if (doW) {
      const int R0 = off >> 2;           // 0 (h0) or 2 (h1)
      float s[8];
      #pragma unroll
      for (int rq = 0; rq < 2; ++rq) {
        const float4 r0 = red[R0+rq][0][lane], r1 = red[R0+rq][1][lane];
        const float4 r2 = red[R0+rq][2][lane], r3 = red[R0+rq][3][lane];
        s[4*rq+0] = (r0.x + r1.x) + (r2.x + r3.x);
        s[4*rq+1] = (r0.y + r1.y) + (r2.y + r3.y);
        s[4*rq+2] = (r0.z + r1.z) + (r2.z + r3.z);
        s[4*rq+3] = (r0.w + r1.w) + (r2.w + r3.w);
      }
      float w[8];
      w[0] = s[0] * __expf(iv0.x - cl[off+0]);
      w[1] = s[1] * __expf(iv0.y - cl[off+1]);
      w[2] = s[2] * __expf(iv0.z - cl[off+2]);
      w[3] = s[3] * __expf(iv0.w - cl[off+3]);
      w[4] = s[4] * __expf(iv1.x - cl[off+4]);
      w[5] = s[5] * __expf(iv1.y - cl[off+5]);
      w[6] = s[6] * __expf(iv1.z - cl[off+6]);
      w[7] = s[7] * __expf(iv1.w - cl[off+7]);
      float cs[8];
      #pragma unroll
      for (int i = 0; i < 8; ++i) cs[i] = w[i];
      #pragma unroll
      for (int o = 32; o; o >>= 1) {
        #pragma unroll
        for (int i = 0; i < 8; ++i) cs[i] += __shfl_xor(cs[i], o);
      }
      float* slot = (exact ? wmain : wscr) + (size_t)tw * WSLOT;
      const int G = 4 * sblk + R0;       // first float4-group
      unsigned long long* wdA = (unsigned long long*)((float4*)slot + (G * 64 + lane));
      unsigned long long* wdB = (unsigned long long*)((float4*)slot + ((G + 1) * 64 + lane));
      union { float2 f; unsigned long long u; } p0, p1, p2, p3;
      p0.f = make_float2(w[0] / cs[0], w[1] / cs[1]);
      p1.f = make_float2(w[2] / cs[2], w[3] / cs[3]);
      p2.f = make_float2(w[4] / cs[4], w[5] / cs[5]);
      p3.f = make_float2(w[6] / cs[6], w[7] / cs[7]);
      __hip_atomic_store(wdA,     p0.u, __ATOMIC_RELAXED, __HIP_MEMORY_SCOPE_AGENT);
      __hip_atomic_store(wdA + 1, p1.u, __ATOMIC_RELAXED, __HIP_MEMORY_SCOPE_AGENT);
      __hip_atomic_store(wdB,     p2.u, __ATOMIC_RELAXED, __HIP_MEMORY_SCOPE_AGENT);
      __hip_atomic_store(wdB + 1, p3.u, __ATOMIC_RELAXED, __HIP_MEMORY_SCOPE_AGENT);
      asm volatile("s_waitcnt vmcnt(0)" ::: "memory");  // w acked at L3
      if (lane == 0)
        __hip_atomic_store(((h == 0) ? flagL : flagH) + sblk, (unsigned)(kk + 1),
                           __ATOMIC_RELAXED, __HIP_MEMORY_SCOPE_AGENT);
    } else if (doD) {
      float dp = 0.f;
      {
        const float4 r0 = red[0][0][lane], r1 = red[0][1][lane];
        const float4 r2 = red[0][2][lane], r3 = red[0][3][lane];
        dp += ((r0.x+r1.x)+(r2.x+r3.x)) * __expf(iv0.x - cl[0]);
        dp += ((r0.y+r1.y)+(r2.y+r3.y)) * __expf(iv0.y - cl[1]);
        dp += ((r0.z+r1.z)+(r2.z+r3.z)) * __expf(iv0.z - cl[2]);
        dp += ((r0.w+r1.w)+(r2.w+r3.w)) * __expf(iv0.w - cl[3]);
      }
      {
        const float4 r0 = red[1][0][lane], r1 = red[1][1][lane];
        const float4 r2 = red[1][2][lane], r3 = red[1][3][lane];
        dp += ((r0.x+r1.x)+(r2.x+r3.x)) * __expf(iv1.x - cl[4]);
        dp += ((r0.y+r1.y)+(r2.y+r3.y)) * __expf(iv1.y - cl[5]);
        dp += ((r0.z+r1.z)+(r2.z+r3.z)) * __expf(iv1.z - cl[6]);
        dp += ((r0.w+r1.w)+(r2.w+r3.w)) * __expf(iv1.w - cl[7]);
      }
      {
        const float4 r0 = red[2][0][lane], r1 = red[2][1][lane];
        const float4 r2 = red[2][2][lane], r3 = red[2][3][lane];
        dp += ((r0.x+r1.x)+(r2.x+r3.x)) * __expf(iv2.x - cl[8]);
        dp += ((r0.y+r1.y)+(r2.y+r3.y)) * __expf(iv2.y - cl[9]);
        dp += ((r0.z+r1.z)+(r2.z+r3.z)) * __expf(iv2.z - cl[10]);
        dp += ((r0.w+r1.w)+(r2.w+r3.w)) * __expf(iv2.w - cl[11]);
      }
      {
        const float4 r0 = red[3][0][lane], r1 = red[3][1][lane];
        const float4 r2 = red[3][2][lane], r3 = red[3][3][lane];
        dp += ((r0.x+r1.x)+(r2.x+r3.x)) * __expf(iv3.x - cl[12]);
        dp += ((r0.y+r1.y)+(r2.y+r3.y)) * __expf(iv3.y - cl[13]);
        dp += ((r0.z+r1.z)+(r2.z+r3.z)) * __expf(iv3.z - cl[14]);
        dp += ((r0.w+r1.w)+(r2.w+r3.w)) * __expf(iv3.w - cl[15]);
      }
      // plain store: k_final is a separate kernel (boundary flush)
      dotpart[((size_t)(tw - 1) * 32 + sblk) * 64 + lane] = dp;
    }
  }
}

// ---------------- final reduction ----------------
__global__ void k_final(const float* __restrict__ dotpart, const float* __restrict__ masks,
                        float* __restrict__ out) {
  const int t = blockIdx.x;    // 256
  const int tid = threadIdx.x; // 256
  const int b = tid & 63, g = tid >> 6;
  float sum = 0.f;
  for (int s = g; s < 32; s += 4) sum += dotpart[((size_t)t * 32 + s) * 64 + b];
  __shared__ float red[4][64];
  red[g][b] = sum;
  __syncthreads();
  if (g == 0) {
    float tot = (red[0][b] + red[1][b]) + (red[2][b] + red[3][b]);
    float v = __logf(tot) * masks[b * TT + t];
    #pragma unroll
    for (int o = 32; o; o >>= 1) v += __shfl_xor(v, o);
    if (b == 0) atomicAdd(out, v);
  }
}

extern "C" void kernel_launch(void* const* d_in, const int* in_sizes, int n_in,
                              void* d_out, int out_size, void* d_ws, size_t ws_size,
                              hipStream_t stream) {
  const int* sent = (const int*)d_in[0];     // [64][256] int32
  const float* masks = (const float*)d_in[1];// [64][256]
  const float* iw = (const float*)d_in[2];   // [32000][512]
  const float* trans = (const float*)d_in[3];// [512][512]
  const float* begin = (const float*)d_in[4];// [512]
  float* out = (float*)d_out;
  float* ws = (float*)d_ws;

  // workspace carve (floats)
  float* P = ws;                             // 262144
  float* psum = P + 262144;                  // 500*512 = 256000
  float* colsum = psum + 256000;             // 512
  float* q0vec = colsum + 512;               // 512
  float* dotpart = q0vec + 512;              // 256*32*64 = 524288
  unsigned* flags = (unsigned*)(dotpart + 524288); // 512
  float* wring = (float*)flags + 512;        // 2 * 256 * 32768 (~67 MB: main+scratch)
  // total ~71 MB

  k_colpart<<<250, 256, 0, stream>>>(iw, psum, out, colsum, flags);
  k_colreduce<<<25, 512, 0, stream>>>(psum, colsum);
  k_transP<<<512, 64, 0, stream>>>(trans, begin, P, q0vec);

  {
    const float* Pp = P;
    const float* q0p = q0vec;
    const float* iwp = iw;
    const float* csp = colsum;
    const int* sentp = sent;
    float* wrp = wring;
    float* dpp = dotpart;
    unsigned* fp = flags;
    void* args[] = {&Pp, &q0p, &iwp, &csp, &sentp, &wrp, &dpp, &fp};
    (void)hipLaunchCooperativeKernel((const void*)k_persist, dim3(256), dim3(256),
                                     args, 0, stream);
  }

  k_final<<<TT, 256, 0, stream>>>(dotpart, masks, out);
}

// Round 9
// 1384.328 us; speedup vs baseline: 1.5351x; 1.5351x over previous
//
#include <hip/hip_runtime.h>
#include <math.h>

// Problem constants
#define VV 32000   // vocab
#define SS 512     // states
#define BB 64      // batch
#define TT 256     // maxlen
#define WSLOT (BB * SS)  // floats per w time-slot (32768)
#define B_BURN 24  // burn-in steps (contraction ~0.46^24 ~ 2e-8; R8: absmax 0.0)

// ---------------- setup kernels ----------------

// Column sums of exp(iw) over vocab rows. Block 0 also hosts one-time zero
// duties (out, colsum, flags) — consumers run in later kernels (stream order).
__global__ void k_colpart(const float* __restrict__ iw, float* __restrict__ psum,
                          float* __restrict__ out, float* __restrict__ colsum,
                          unsigned* __restrict__ flags) {
  const int blk = blockIdx.x;        // 250
  const int tid = threadIdx.x;       // 256
  if (blk == 0) {
    if (tid == 0) out[0] = 0.f;
    flags[tid] = 0u; flags[tid + 256] = 0u;       // 512 flags (4 segs x (64L+64H))
    colsum[tid] = 0.f; colsum[tid + 256] = 0.f;
  }
  const int cg = tid & 127;          // float4 column group
  const int rh = tid >> 7;           // row half
  const int r0 = blk * 128 + rh * 64;
  const float4* iw4 = (const float4*)iw;   // [32000][128] float4
  float4 s = make_float4(0.f, 0.f, 0.f, 0.f);
  #pragma unroll 4
  for (int r = 0; r < 64; ++r) {
    float4 x = iw4[(size_t)(r0 + r) * 128 + cg];
    s.x += __expf(x.x); s.y += __expf(x.y); s.z += __expf(x.z); s.w += __expf(x.w);
  }
  ((float4*)psum)[(size_t)(blk * 2 + rh) * 128 + cg] = s;
}

// 25 blocks x 512 thr: block p sums partial rows [20p, 20p+20) -> atomicAdd.
__global__ void k_colreduce(const float* __restrict__ psum, float* __restrict__ colsum) {
  const int c = threadIdx.x;         // 512
  const int p0 = blockIdx.x * 20;
  float s = 0.f;
  #pragma unroll 5
  for (int p = 0; p < 20; ++p) s += psum[(size_t)(p0 + p) * SS + c];
  atomicAdd(&colsum[c], s);
}

// P[i][j] = softmax(transition[i,:])[j] (row-major), q0vec[i] = sum_j P[i,j]*sb[j].
__global__ void k_transP(const float* __restrict__ trans, const float* __restrict__ begin,
                         float* __restrict__ P, float* __restrict__ q0vec) {
  const int i = blockIdx.x;     // 512 rows
  const int lane = threadIdx.x; // 64
  // local softmax(begin)
  float bx[8];
  float bm = -1e30f;
  #pragma unroll
  for (int cc = 0; cc < 8; ++cc) { bx[cc] = begin[cc * 64 + lane]; bm = fmaxf(bm, bx[cc]); }
  #pragma unroll
  for (int o = 32; o; o >>= 1) bm = fmaxf(bm, __shfl_xor(bm, o));
  float bs = 0.f;
  #pragma unroll
  for (int cc = 0; cc < 8; ++cc) { bx[cc] = __expf(bx[cc] - bm); bs += bx[cc]; }
  #pragma unroll
  for (int o = 32; o; o >>= 1) bs += __shfl_xor(bs, o);
  const float binv = 1.f / bs;

  const float* rp = trans + (size_t)i * SS;
  float xs[8];
  float m = -1e30f;
  #pragma unroll
  for (int cc = 0; cc < 8; ++cc) { xs[cc] = rp[cc * 64 + lane]; m = fmaxf(m, xs[cc]); }
  #pragma unroll
  for (int o = 32; o; o >>= 1) m = fmaxf(m, __shfl_xor(m, o));
  float s = 0.f;
  #pragma unroll
  for (int cc = 0; cc < 8; ++cc) s += __expf(xs[cc] - m);
  #pragma unroll
  for (int o = 32; o; o >>= 1) s += __shfl_xor(s, o);
  const float lse = m + __logf(s);
  float qa = 0.f;
  #pragma unroll
  for (int cc = 0; cc < 8; ++cc) {
    float p = __expf(xs[cc] - lse);
    P[(size_t)i * SS + cc * 64 + lane] = p;
    qa += p * (bx[cc] * binv);
  }
  #pragma unroll
  for (int o = 32; o; o >>= 1) qa += __shfl_xor(qa, o);
  if (lane == 0) q0vec[i] = qa;
}

// ---------------- persistent segmented-chain kernel ----------------
// 256 blocks = 4 segments x 64 blocks. seg = blk&3 (segment spans 2 XCDs:
// blk%8 in {seg, seg+4} — locality heuristic only). seg -> (chain c = seg&1,
// half q = seg>>1). Chain-even k-ranges: [0,65) [65,129); chain-odd: [0,64)
// [64,128). q=1 segments prepend B_BURN burn-in steps from uniform w=1/64
// (valid: batch-col-sums = 1; P rows sum to 1 => P*w = 1/64). Burn-in writes
// a PRIVATE scratch ring and skips dotpart; Birkhoff contraction kills the
// init error (R8: bit-identical output). Chain latency 129 -> 88 steps.
//
// Each block owns 8 states. Sync fabric = R3/R7's proven 3-barrier shape:
// single sleepy scout (wave 0, s_sleep(2)) polls its segment's 64 L + 64 H
// flags (2 coalesced loads + __all, own-flag skip) between two barriers; all
// other waves parked. Producers: wave0 -> states [i0,i0+4) + flagL, wave1 ->
// [i0+4,i0+8) + flagH (each: 2x8B agent stores, vmcnt(0) ack, flag);
// wave2 -> dotpart. launch_bounds(256,1): 1 block/CU, VGPR up to 512 —
// R8's regression was the compiler's 128-VGPR cap + spills at 16 states.
__global__ __launch_bounds__(256, 1) void k_persist(
    const float* __restrict__ P, const float* __restrict__ q0vec,
    const float* __restrict__ iw, const float* __restrict__ colsum,
    const int* __restrict__ sent, float* __restrict__ wring,
    float* __restrict__ dotpart, unsigned* __restrict__ flags) {
  const int blk = blockIdx.x;
  const int seg = blk & 3;
  const int sblk = blk >> 2;           // 0..63
  const int c = seg & 1;
  const int q = seg >> 1;              // 0..1
  const int lane = threadIdx.x & 63;   // batch b
  const int h = __builtin_amdgcn_readfirstlane(threadIdx.x >> 6);
  const int i0 = sblk << 3;            // 8 states per block

  const int kend = c ? (q ? 128 : 64) : (q ? 129 : 65);
  const int kbeg = q ? (c ? 64 : 65) : 0;
  const int kfirst = q ? (kbeg - B_BURN) : 0;

  unsigned* const flagL = flags + seg * 64;
  unsigned* const flagH = flags + 256 + seg * 64;
  const bool own = (lane == sblk);

  float cl[8];
  #pragma unroll
  for (int r = 0; r < 8; ++r) cl[r] = __logf(colsum[i0 + r]);

  const float4* Pq[8];
  #pragma unroll
  for (int r = 0; r < 8; ++r)
    Pq[r] = (const float4*)(P + (size_t)(i0 + r) * SS) + h * 32;

  float* const wmain = wring;
  float* const wscr  = wring + (size_t)TT * WSLOT;

  __shared__ float4 red[2][4][64];   // [state-quad][wave][lane]

  for (int kk = kfirst; kk < kend; ++kk) {
    const int tw = 2 * kk + c;
    const bool exact = (kk >= kbeg);
    const bool doW = (h <= 1) && (kk + 1 < kend);
    const bool doD = (h == 2) && exact && (tw >= 1);

    // iw gathers issued before the sync phase — L2/L3 latency hides there.
    float4 iv0 = make_float4(0.f, 0.f, 0.f, 0.f), iv1 = iv0;
    if (doW) {
      const int row = sent[lane * TT + tw];
      iv0 = *(const float4*)(iw + (size_t)row * SS + i0 + 4 * h);
    } else if (doD) {
      const int row = sent[lane * TT + (tw - 1)];
      const float* ip = iw + (size_t)row * SS + i0;
      iv0 = *(const float4*)ip;
      iv1 = *(const float4*)(ip + 4);
    }

    if (kk > kfirst) {
      __syncthreads();  // previous epilogue + red reads complete
      if (h == 0) {
        const unsigned tgt = (unsigned)kk;  // predecessor stored kk at step kk-1
        for (;;) {
          const unsigned va = __hip_atomic_load(flagL + lane, __ATOMIC_RELAXED,
                                                __HIP_MEMORY_SCOPE_AGENT);
          const unsigned vb = __hip_atomic_load(flagH + lane, __ATOMIC_RELAXED,
                                                __HIP_MEMORY_SCOPE_AGENT);
          if (__all(own || ((va >= tgt) && (vb >= tgt)))) break;
          __builtin_amdgcn_s_sleep(2);
        }
      }
      __syncthreads();
    }

    float a[8];
    if (kk == 0) {                       // exact init (q=0 segments)
      #pragma unroll
      for (int r = 0; r < 8; ++r) a[r] = (h == 0) ? q0vec[i0 + r] : 0.f;
    } else if (kk == kfirst) {           // burn-in init: w_prev = 1/64 uniform
      #pragma unroll
      for (int r = 0; r < 8; ++r) a[r] = (h == 0) ? 0.015625f : 0.f;
    } else {
      const float* wsrc = ((kk - 1) >= kbeg) ? wmain : wscr;
      const float4* wv = (const float4*)(wsrc + (size_t)(tw - 2) * WSLOT)
                         + h * 32 * 64;
      #pragma unroll
      for (int r = 0; r < 8; ++r) a[r] = 0.f;
      // Full-depth prefetch: all 32 w float4 loads in flight, then the FMA
      // stream against L1/L2-resident P rows. ~160 VGPR, no spill at 1 blk/CU.
      float4 wr[32];
      #pragma unroll
      for (int u = 0; u < 32; ++u) wr[u] = wv[u * 64 + lane];
      #pragma unroll
      for (int u = 0; u < 32; ++u) {
        #pragma unroll
        for (int r = 0; r < 8; ++r) {
          const float4 p = Pq[r][u];
          a[r] += wr[u].x * p.x + wr[u].y * p.y + wr[u].z * p.z + wr[u].w * p.w;
        }
      }
    }

    red[0][h][lane] = make_float4(a[0], a[1], a[2], a[3]);
    red[1][h][lane] = make_float4(a[4], a[5], a[6], a[7]);
    __syncthreads();

    if (doW) {
      // producer wave h handles state-quad h (states i0+4h .. i0+4h+3)
      const float4 r0 = red[h][0][lane], r1 = red[h][1][lane];
      const float4 r2 = red[h][2][lane], r3 = red[h][3][lane];
      float s0 = (r0.x + r1.x) + (r2.x + r3.x);
      float s1 = (r0.y + r1.y) + (r2.y + r3.y);
      float s2 = (r0.z + r1.z) + (r2.z + r3.z);
      float s3 = (r0.w + r1.w) + (r2.w + r3.w);
      const int o4 = 4 * h;
      float w0 = s0 * __expf(iv0.x - cl[o4 + 0]);
      float w1 = s1 * __expf(iv0.y - cl[o4 + 1]);
      float w2 = s2 * __expf(iv0.z - cl[o4 + 2]);
      float w3 = s3 * __expf(iv0.w - cl[o4 + 3]);
      float c0 = w0, c1 = w1, c2 = w2, c3 = w3;
      #pragma unroll
      for (int o = 32; o; o >>= 1) {
        c0 += __shfl_xor(c0, o);
        c1 += __shfl_xor(c1, o);
        c2 += __shfl_xor(c2, o);
        c3 += __shfl_xor(c3, o);
      }
      // write-through (agent) stores: data reaches L3 (coherence point)
      float* slot = (exact ? wmain : wscr) + (size_t)tw * WSLOT;
      const int G = 2 * sblk + h;      // float4-group index
      unsigned long long* wd = (unsigned long long*)((float4*)slot + (G * 64 + lane));
      union { float2 f; unsigned long long u; } lo, hi;
      lo.f = make_float2(w0 / c0, w1 / c1);
      hi.f = make_float2(w2 / c2, w3 / c3);
      __hip_atomic_store(wd,     lo.u, __ATOMIC_RELAXED, __HIP_MEMORY_SCOPE_AGENT);
      __hip_atomic_store(wd + 1, hi.u, __ATOMIC_RELAXED, __HIP_MEMORY_SCOPE_AGENT);
      asm volatile("s_waitcnt vmcnt(0)" ::: "memory");  // w acked at L3
      if (lane == 0)
        __hip_atomic_store(((h == 0) ? flagL : flagH) + sblk, (unsigned)(kk + 1),
                           __ATOMIC_RELAXED, __HIP_MEMORY_SCOPE_AGENT);
    } else if (doD) {
      float dp = 0.f;
      {
        const float4 r0 = red[0][0][lane], r1 = red[0][1][lane];
        const float4 r2 = red[0][2][lane], r3 = red[0][3][lane];
        dp += ((r0.x + r1.x) + (r2.x + r3.x)) * __expf(iv0.x - cl[0]);
        dp += ((r0.y + r1.y) + (r2.y + r3.y)) * __expf(iv0.y - cl[1]);
        dp += ((r0.z + r1.z) + (r2.z + r3.z)) * __expf(iv0.z - cl[2]);
        dp += ((r0.w + r1.w) + (r2.w + r3.w)) * __expf(iv0.w - cl[3]);
      }
      {
        const float4 r0 = red[1][0][lane], r1 = red[1][1][lane];
        const float4 r2 = red[1][2][lane], r3 = red[1][3][lane];
        dp += ((r0.x + r1.x) + (r2.x + r3.x)) * __expf(iv1.x - cl[4]);
        dp += ((r0.y + r1.y) + (r2.y + r3.y)) * __expf(iv1.y - cl[5]);
        dp += ((r0.z + r1.z) + (r2.z + r3.z)) * __expf(iv1.z - cl[6]);
        dp += ((r0.w + r1.w) + (r2.w + r3.w)) * __expf(iv1.w - cl[7]);
      }
      // plain store: k_final is a separate kernel (boundary flush)
      dotpart[((size_t)(tw - 1) * 64 + sblk) * 64 + lane] = dp;
    }
  }
}

// ---------------- final reduction ----------------
__global__ void k_final(const float* __restrict__ dotpart, const float* __restrict__ masks,
                        float* __restrict__ out) {
  const int t = blockIdx.x;    // 256
  const int tid = threadIdx.x; // 256
  const int b = tid & 63, g = tid >> 6;
  float sum = 0.f;
  for (int s = g; s < 64; s += 4) sum += dotpart[((size_t)t * 64 + s) * 64 + b];
  __shared__ float red[4][64];
  red[g][b] = sum;
  __syncthreads();
  if (g == 0) {
    float tot = (red[0][b] + red[1][b]) + (red[2][b] + red[3][b]);
    float v = __logf(tot) * masks[b * TT + t];
    #pragma unroll
    for (int o = 32; o; o >>= 1) v += __shfl_xor(v, o);
    if (b == 0) atomicAdd(out, v);
  }
}

extern "C" void kernel_launch(void* const* d_in, const int* in_sizes, int n_in,
                              void* d_out, int out_size, void* d_ws, size_t ws_size,
                              hipStream_t stream) {
  const int* sent = (const int*)d_in[0];     // [64][256] int32
  const float* masks = (const float*)d_in[1];// [64][256]
  const float* iw = (const float*)d_in[2];   // [32000][512]
  const float* trans = (const float*)d_in[3];// [512][512]
  const float* begin = (const float*)d_in[4];// [512]
  float* out = (float*)d_out;
  float* ws = (float*)d_ws;

  // workspace carve (floats)
  float* P = ws;                             // 262144
  float* psum = P + 262144;                  // 500*512 = 256000
  float* colsum = psum + 256000;             // 512
  float* q0vec = colsum + 512;               // 512
  float* dotpart = q0vec + 512;              // 256*64*64 = 1048576
  unsigned* flags = (unsigned*)(dotpart + 1048576); // 512
  float* wring = (float*)flags + 512;        // 2 * 256 * 32768 (~67 MB: main+scratch)
  // total ~73 MB

  k_colpart<<<250, 256, 0, stream>>>(iw, psum, out, colsum, flags);
  k_colreduce<<<25, 512, 0, stream>>>(psum, colsum);
  k_transP<<<512, 64, 0, stream>>>(trans, begin, P, q0vec);

  {
    const float* Pp = P;
    const float* q0p = q0vec;
    const float* iwp = iw;
    const float* csp = colsum;
    const int* sentp = sent;
    float* wrp = wring;
    float* dpp = dotpart;
    unsigned* fp = flags;
    void* args[] = {&Pp, &q0p, &iwp, &csp, &sentp, &wrp, &dpp, &fp};
    (void)hipLaunchCooperativeKernel((const void*)k_persist, dim3(256), dim3(256),
                                     args, 0, stream);
  }

  k_final<<<TT, 256, 0, stream>>>(dotpart, masks, out);
}